// Round 5
// baseline (405.158 us; speedup 1.0000x reference)
//
#include <hip/hip_runtime.h>
#include <hip/hip_bf16.h>

// B=2, T=2048, C=2048, H=16, HD=128
#define B_  2
#define T_  2048
#define C_  2048
#define H_  16
#define HD_ 128

using bf16x8 = __attribute__((ext_vector_type(8))) __bf16;
using f32x4  = __attribute__((ext_vector_type(4))) float;

__device__ __forceinline__ unsigned short f2bs(float f) {
    __hip_bfloat16 h = __float2bfloat16(f);
    return __builtin_bit_cast(unsigned short, h);
}

// async global->LDS, 16B per lane; LDS dest = wave-uniform base + lane*16
__device__ __forceinline__ void gload_lds16(const unsigned short* g, unsigned short* l) {
    __builtin_amdgcn_global_load_lds(
        (const __attribute__((address_space(1))) unsigned int*)g,
        (__attribute__((address_space(3))) unsigned int*)l, 16, 0, 0);
}

// ---------------- merged prep: fp32->bf16 convert + 2 weight transposes ----------------
// blocks [0,8192): x convert; [8192,11264): Wqkv^T; [11264,12288): Wproj^T
__global__ __launch_bounds__(256) void k_prep(const float* __restrict__ x,
                                              unsigned short* __restrict__ XB,
                                              const float* __restrict__ Wqkv,
                                              unsigned short* __restrict__ WQKVT,
                                              const float* __restrict__ Wproj,
                                              unsigned short* __restrict__ WPROJT) {
    __shared__ unsigned short t[64][65];
    int blk = blockIdx.x;
    int tid = threadIdx.x;
    if (blk < 8192) {
        int i = blk * 256 + tid;
        float4 v = reinterpret_cast<const float4*>(x)[i];
        ushort4 o;
        o.x = f2bs(v.x); o.y = f2bs(v.y); o.z = f2bs(v.z); o.w = f2bs(v.w);
        reinterpret_cast<ushort4*>(XB)[i] = o;
        return;
    }
    const float* in;
    unsigned short* out;
    int K = 2048, N, bx, by;
    if (blk < 11264) {
        in = Wqkv; out = WQKVT; N = 6144;
        bx = (blk - 8192) % 96; by = (blk - 8192) / 96;
    } else {
        in = Wproj; out = WPROJT; N = 2048;
        bx = (blk - 11264) % 32; by = (blk - 11264) / 32;
    }
    int k0 = by * 64, n0 = bx * 64;
#pragma unroll
    for (int p = 0; p < 4; ++p) {
        int idx = p * 256 + tid;
        int r = idx >> 4, c = (idx & 15) << 2;
        float4 v = *reinterpret_cast<const float4*>(in + (long)(k0 + r) * N + n0 + c);
        t[r][c] = f2bs(v.x); t[r][c + 1] = f2bs(v.y);
        t[r][c + 2] = f2bs(v.z); t[r][c + 3] = f2bs(v.w);
    }
    __syncthreads();
#pragma unroll
    for (int p = 0; p < 4; ++p) {
        int idx = p * 256 + tid;
        int r = idx >> 4, c = (idx & 15) << 2;
        ushort4 o;
        o.x = t[c][r]; o.y = t[c + 1][r]; o.z = t[c + 2][r]; o.w = t[c + 3][r];
        *reinterpret_cast<ushort4*>(out + (long)(n0 + r) * K + k0 + c) = o;
    }
}

// ---------------- GEMM: A[M][K] bf16 x Bt[N][K] bf16 -> epilogue per MODE ----------------
// 128x128 tile, BK=64 as two BK=32 sub-buffers, global_load_lds width-16 staging.
// MODE 0: write qkv, Q/K as [bh][T][HD], V transposed as [bh][HD][T].
// MODE 1: out fp32 [M][N] + bias.
template <int MODE>
__global__ __launch_bounds__(256, 2) void k_gemm(const unsigned short* __restrict__ A,
                                                 const unsigned short* __restrict__ Bt,
                                                 int M, int N, int K,
                                                 unsigned short* __restrict__ qkv,
                                                 float* __restrict__ out,
                                                 const float* __restrict__ bias) {
    __shared__ __align__(16) unsigned short lA[2][128 * 32];
    __shared__ __align__(16) unsigned short lB[2][128 * 32];

    int tid = threadIdx.x;
    int wave = tid >> 6, lane = tid & 63;
    int quad = lane >> 4, l16 = lane & 15;
    int wr = (wave >> 1) * 64, wc = (wave & 1) * 64;
    int m0 = blockIdx.y * 128, n0 = blockIdx.x * 128;

    int lrow = lane >> 2;          // 0..15
    int lcol = (lane & 3) << 3;    // 0,8,16,24
    const unsigned short* gA0 = A + (long)(m0 + wave * 32 + lrow) * K + lcol;
    const unsigned short* gA1 = A + (long)(m0 + wave * 32 + 16 + lrow) * K + lcol;
    const unsigned short* gB0 = Bt + (long)(n0 + wave * 32 + lrow) * K + lcol;
    const unsigned short* gB1 = Bt + (long)(n0 + wave * 32 + 16 + lrow) * K + lcol;
    int lofs0 = wave * 1024, lofs1 = wave * 1024 + 512;

    f32x4 zero = {0.f, 0.f, 0.f, 0.f};
    f32x4 acc[4][4];
#pragma unroll
    for (int i = 0; i < 4; ++i)
#pragma unroll
        for (int j = 0; j < 4; ++j) acc[i][j] = zero;

    for (int k0 = 0; k0 < K; k0 += 64) {
        __syncthreads();
#pragma unroll
        for (int h = 0; h < 2; ++h) {
            int kk = k0 + h * 32;
            gload_lds16(gA0 + kk, &lA[h][lofs0]);
            gload_lds16(gA1 + kk, &lA[h][lofs1]);
            gload_lds16(gB0 + kk, &lB[h][lofs0]);
            gload_lds16(gB1 + kk, &lB[h][lofs1]);
        }
        __syncthreads();
#pragma unroll
        for (int h = 0; h < 2; ++h) {
            bf16x8 af[4], bfr[4];
#pragma unroll
            for (int i = 0; i < 4; ++i)
                af[i] = *reinterpret_cast<const bf16x8*>(&lA[h][(wr + i * 16 + l16) * 32 + quad * 8]);
#pragma unroll
            for (int j = 0; j < 4; ++j)
                bfr[j] = *reinterpret_cast<const bf16x8*>(&lB[h][(wc + j * 16 + l16) * 32 + quad * 8]);
#pragma unroll
            for (int i = 0; i < 4; ++i)
#pragma unroll
                for (int j = 0; j < 4; ++j)
                    acc[i][j] = __builtin_amdgcn_mfma_f32_16x16x32_bf16(af[i], bfr[j], acc[i][j], 0, 0, 0);
        }
    }

#pragma unroll
    for (int i = 0; i < 4; ++i) {
#pragma unroll
        for (int j = 0; j < 4; ++j) {
#pragma unroll
            for (int r = 0; r < 4; ++r) {
                int m = m0 + wr + i * 16 + quad * 4 + r;
                int n = n0 + wc + j * 16 + l16;
                float v = acc[i][j][r];
                if (MODE == 0) {
                    int s = n >> 11, col = n & 2047;
                    int h = col >> 7, hd = col & 127;
                    int b = m >> 11, t = m & 2047;
                    long base = (long)s * (B_ * H_ * T_ * HD_);
                    if (s == 2)  // V stored transposed: [bh][HD][T]
                        qkv[base + ((long)(b * H_ + h) * HD_ + hd) * T_ + t] = f2bs(v);
                    else
                        qkv[base + ((long)(b * H_ + h) * T_ + t) * HD_ + hd] = f2bs(v);
                } else {
                    out[(long)m * N + n] = v + bias[n];
                }
            }
        }
    }
}

// ---------------- flash attention ----------------
// qkv: Q,K [bh][T][HD], V [bh][HD][T] (pre-transposed), all bf16 -> y [B*T][C] bf16
// block: 4 waves, 64 q-rows (16/wave), kv-step 64. Grid (bh=32, qtile=32), longest-first.
// K/Vt staged via global_load_lds into 32-wide chunked layouts (conflict-free, m97 pattern).
__global__ __launch_bounds__(256, 3) void k_attn(const unsigned short* __restrict__ qkv,
                                                 unsigned short* __restrict__ y) {
    __shared__ __align__(16) unsigned short lK[4][64 * 32];    // [hd-chunk][key][32]
    __shared__ __align__(16) unsigned short lVt[2][128 * 32];  // [key-chunk][hd][32]
    __shared__ __align__(16) unsigned short lP[4][16 * 72];    // per-wave P [qrow][key], padded

    int tid = threadIdx.x;
    int wave = tid >> 6, lane = tid & 63;
    int quad = lane >> 4, l16 = lane & 15;
    int bh = blockIdx.x;                          // 0..31
    int qb = ((int)gridDim.y - 1 - (int)blockIdx.y) * 64;  // heavy tiles dispatch first

    const unsigned short* Qh = qkv + (long)bh * (T_ * HD_);
    const unsigned short* Kh = qkv + (long)(B_ * H_) * T_ * HD_ + (long)bh * (T_ * HD_);
    const unsigned short* Vt = qkv + 2L * (B_ * H_) * T_ * HD_ + (long)bh * (HD_ * T_);

    // preload this wave's 16 Q rows as A-fragments (A[m=l16][k=quad*8+j], 4 k-steps)
    bf16x8 aQ[4];
    int qrow = qb + wave * 16 + l16;
#pragma unroll
    for (int kk = 0; kk < 4; ++kk)
        aQ[kk] = *reinterpret_cast<const bf16x8*>(Qh + (long)qrow * HD_ + kk * 32 + quad * 8);

    // staging addresses: lane -> row lane/4, col (lane&3)*8 within a 32-wide chunk
    int lrow = lane >> 2, lcol = (lane & 3) << 3;
    const unsigned short* gK = Kh + (long)(wave * 16 + lrow) * HD_ + lcol;  // wave stages keys w*16..+15
    const unsigned short* gV = Vt + (long)(wave * 32 + lrow) * T_ + lcol;   // wave stages hd w*32..+31

    float m_s[4], l_s[4];
    f32x4 O[8];
    f32x4 zero = {0.f, 0.f, 0.f, 0.f};
#pragma unroll
    for (int r = 0; r < 4; ++r) { m_s[r] = -1e30f; l_s[r] = 0.f; }
#pragma unroll
    for (int h = 0; h < 8; ++h) O[h] = zero;

    int qmax = qb + wave * 16 + 15;
    const float scl2 = 0.1275174365f;  // 1/sqrt(128) * log2(e)  (log2-domain softmax)

    for (int kb = 0; kb < qb + 64; kb += 64) {
        __syncthreads();
        // K tile: 4 hd-chunks, wave stages its 16 key-rows per chunk (1 inst each)
#pragma unroll
        for (int kk = 0; kk < 4; ++kk)
            gload_lds16(gK + kb * HD_ + kk * 32, &lK[kk][wave * 512]);
        // Vt tile: 2 key-chunks, wave stages its 32 hd-rows (2 insts each)
#pragma unroll
        for (int kc = 0; kc < 2; ++kc) {
            gload_lds16(gV + kb + kc * 32, &lVt[kc][wave * 1024]);
            gload_lds16(gV + 16 * T_ + kb + kc * 32, &lVt[kc][wave * 1024 + 512]);
        }
        __syncthreads();  // vmcnt(0) drain
        if (kb > qmax) continue;  // wave-uniform skip; staging+barriers already done

        // S = Q K^T : 4 key-subtiles of 16, 4 hd-chunks each
        f32x4 s[4];
#pragma unroll
        for (int st = 0; st < 4; ++st) s[st] = zero;
#pragma unroll
        for (int kk = 0; kk < 4; ++kk) {
#pragma unroll
            for (int st = 0; st < 4; ++st) {
                bf16x8 b = *reinterpret_cast<const bf16x8*>(
                    &lK[kk][(st * 16 + l16) * 32 + quad * 8]);
                s[st] = __builtin_amdgcn_mfma_f32_16x16x32_bf16(aQ[kk], b, s[st], 0, 0, 0);
            }
        }

        // online softmax (log2 domain); l_s kept as PER-LANE partial (reduced in epilogue)
        int qg = qb + wave * 16 + quad * 4;
#pragma unroll
        for (int r = 0; r < 4; ++r) {
            int q = qg + r;
            float x[4];
#pragma unroll
            for (int st = 0; st < 4; ++st)
                x[st] = (kb + st * 16 + l16 <= q) ? s[st][r] * scl2 : -1e30f;
            float mx = fmaxf(fmaxf(x[0], x[1]), fmaxf(x[2], x[3]));
#pragma unroll
            for (int off = 1; off < 16; off <<= 1) mx = fmaxf(mx, __shfl_xor(mx, off));
            float mn = fmaxf(m_s[r], mx);
            float al = exp2f(m_s[r] - mn);
            float p[4], ps = 0.f;
#pragma unroll
            for (int st = 0; st < 4; ++st) { p[st] = exp2f(x[st] - mn); ps += p[st]; }
            m_s[r] = mn;
            l_s[r] = l_s[r] * al + ps;  // per-lane partial over this lane's 4 columns
            int row = quad * 4 + r;
#pragma unroll
            for (int st = 0; st < 4; ++st)
                lP[wave][row * 72 + st * 16 + l16] = f2bs(p[st]);
#pragma unroll
            for (int h = 0; h < 8; ++h) O[h][r] *= al;
        }

        // P (A-layout) @ V -> O over 8 hd-tiles x 2 key-chunks
#pragma unroll
        for (int kc = 0; kc < 2; ++kc) {
            bf16x8 pf = *reinterpret_cast<const bf16x8*>(
                &lP[wave][l16 * 72 + kc * 32 + quad * 8]);
#pragma unroll
            for (int h = 0; h < 8; ++h) {
                bf16x8 vf = *reinterpret_cast<const bf16x8*>(
                    &lVt[kc][(h * 16 + l16) * 32 + quad * 8]);
                O[h] = __builtin_amdgcn_mfma_f32_16x16x32_bf16(pf, vf, O[h], 0, 0, 0);
            }
        }
    }

    // epilogue: reduce per-lane l_s partials across the 16 lanes of each row, then write
    int b = bh >> 4, hh = bh & 15;
#pragma unroll
    for (int r = 0; r < 4; ++r) {
        float l = l_s[r];
#pragma unroll
        for (int off = 1; off < 16; off <<= 1) l += __shfl_xor(l, off);
        float inv = 1.f / l;
        int t = qb + wave * 16 + quad * 4 + r;
#pragma unroll
        for (int h = 0; h < 8; ++h)
            y[(long)(b * T_ + t) * C_ + hh * HD_ + h * 16 + l16] = f2bs(O[h][r] * inv);
    }
}

extern "C" void kernel_launch(void* const* d_in, const int* in_sizes, int n_in,
                              void* d_out, int out_size, void* d_ws, size_t ws_size,
                              hipStream_t stream) {
    const float* x     = (const float*)d_in[0];
    // d_in[1] = causal mask, ignored (handled analytically)
    const float* Wqkv  = (const float*)d_in[2];
    const float* Wproj = (const float*)d_in[3];
    const float* bproj = (const float*)d_in[4];
    float* out = (float*)d_out;

    // workspace layout (bf16 elements); y aliases XB (XB dead after gemm1)
    unsigned short* XB     = (unsigned short*)d_ws;   // [4096][2048]  (later: y)
    unsigned short* WQKVT  = XB + 8388608;            // [6144][2048]
    unsigned short* WPROJT = WQKVT + 12582912;        // [2048][2048]
    unsigned short* QKV    = WPROJT + 4194304;        // [3][32][...]
    if (ws_size < 100663296) return;                  // 96 MB needed

    k_prep<<<12288, 256, 0, stream>>>(x, XB, Wqkv, WQKVT, Wproj, WPROJT);
    k_gemm<0><<<dim3(6144 / 128, 4096 / 128), 256, 0, stream>>>(XB, WQKVT, 4096, 6144, 2048,
                                                                QKV, nullptr, nullptr);
    k_attn<<<dim3(32, 32), 256, 0, stream>>>(QKV, XB);
    k_gemm<1><<<dim3(2048 / 128, 4096 / 128), 256, 0, stream>>>(XB, WPROJT, 4096, 2048, 2048,
                                                                nullptr, out, bproj);
}